// Round 3
// baseline (264.159 us; speedup 1.0000x reference)
//
#include <hip/hip_runtime.h>
#include <hip/hip_bf16.h>
#include <stdint.h>
#include <string.h>

#define NV 40962     // vertices
#define NC 64        // in channels
#define NO 64        // out channels
#define NM 27        // neighbors*3
#define NB 4         // batch
#define KP 576       // K = 9*64, permuted t = k*64 + c (k-major)
#define ROW 584      // feat LDS row stride (ushorts); 1168 B/row -> 4-bank shift
#define NPAD 28      // padded pairs per vertex (16B-aligned rows: 112 B)

using frag16 = __attribute__((ext_vector_type(8))) short;  // 8 bf16
using f32x4  = __attribute__((ext_vector_type(4))) float;  // MFMA acc
using v2f    = __attribute__((ext_vector_type(2))) float;  // packed fma

__device__ inline float bfbits(unsigned int hi16) {
    union { unsigned int i; float f; } c; c.i = hi16; return c.f;
}
__device__ inline unsigned int pack_bf2(float a, float b) {
    float2 f2 = make_float2(a, b);
    __hip_bfloat162 h = __float22bfloat162_rn(f2);
    unsigned int u; memcpy(&u, &h, 4); return u;
}
__device__ inline unsigned short f2bf16(float f) {
    union { float f; unsigned int i; } c; c.f = f;
    unsigned int x = c.i;
    return (unsigned short)((x + 0x7FFFu + ((x >> 16) & 1u)) >> 16);  // RNE
}
__device__ inline unsigned int comp(const uint4& v, int i) {
    switch (i & 3) { case 0: return v.x; case 1: return v.y; case 2: return v.z; default: return v.w; }
}

// ---- W (64 x 576) fp32 -> Wp bf16, K permuted t = k*64 + c ----
__global__ __launch_bounds__(256) void wprep_kernel(const float* __restrict__ W,
                                                    unsigned short* __restrict__ Wp) {
    int i = blockIdx.x * 256 + threadIdx.x;
    if (i >= NO * KP) return;
    int o = i / KP, t = i % KP;
    int k = t >> 6, c = t & 63;
    Wp[i] = f2bf16(W[o * 576 + c * 9 + k]);
}

// ---- (nidx, nwt) -> packed pairs: uint = (bf16(w) << 16) | idx, padded to 28 ----
__global__ __launch_bounds__(256) void pair_prep(const int* __restrict__ nidx,
                                                 const float* __restrict__ nwt,
                                                 unsigned int* __restrict__ pairs) {
    int i = blockIdx.x * 256 + threadIdx.x;
    if (i >= NV * NPAD) return;
    int v = i / NPAD, j = i - v * NPAD;
    unsigned int pv = 0;
    if (j < NM) {
        unsigned int id = (unsigned int)nidx[v * NM + j];      // < 40962 -> fits 16 bits
        unsigned int wb = (unsigned int)f2bf16(nwt[v * NM + j]);
        pv = (wb << 16) | (id & 0xffffu);
    }
    pairs[i] = pv;
}

// ---- x (B,C,V) fp32 -> xt (B,V,C) bf16 ----
__global__ __launch_bounds__(256) void transpose_kernel(const float* __restrict__ x,
                                                        unsigned short* __restrict__ xt) {
    __shared__ float tile[64][65];
    int b = blockIdx.y;
    int v0 = blockIdx.x * 64;
    int t = threadIdx.x;
    int tv = t & 63, tc = t >> 6;
    const float* xb = x + (size_t)b * NC * NV;
    #pragma unroll
    for (int i = 0; i < 16; i++) {
        int c = tc + i * 4;
        int v = v0 + tv;
        tile[c][tv] = (v < NV) ? xb[(size_t)c * NV + v] : 0.f;
    }
    __syncthreads();
    unsigned short* xtb = xt + (size_t)b * NV * NC;
    #pragma unroll
    for (int i = 0; i < 2; i++) {
        int r = i * 32 + (t >> 3);
        int ch0 = (t & 7) * 8;
        int v = v0 + r;
        if (v < NV) {
            unsigned int o[4];
            #pragma unroll
            for (int j = 0; j < 4; j++)
                o[j] = pack_bf2(tile[ch0 + 2 * j][r], tile[ch0 + 2 * j + 1][r]);
            *(uint4*)(xtb + (size_t)v * NC + ch0) = *(const uint4*)o;
        }
    }
}

// ---- fused gather + MFMA GEMM ----
// block = 128 (2 waves); wave: 16 vertices x 64 outputs.
// Gather: 4 passes x 4 vertices; lane = (vsub = lane>>4, cg = lane&15).
// All 27 gather loads issued before accumulation (u[27] in flight);
// next pass's pair block prefetched during accumulate.
__global__ __launch_bounds__(128, 2) void fused_kernel(
    const unsigned short* __restrict__ xt,
    const unsigned int* __restrict__ pairs,
    const unsigned short* __restrict__ Wp,
    const float* __restrict__ bias,
    float* __restrict__ out)
{
    __shared__ unsigned short feat[32 * ROW];  // 36.5 KB -> 4 blocks/CU
    int wave = threadIdx.x >> 6;
    int lane = threadIdx.x & 63;
    int b = blockIdx.y;
    int n0w = blockIdx.x * 32 + wave * 16;
    const char* xb = (const char*)(xt + (size_t)b * NV * NC);

    int vsub = lane >> 4;        // 0..3
    int cg   = lane & 15;        // channels 4cg..4cg+3 (8 B)
    int cofs = cg * 8;

    // pairs for pass 0
    uint4 pr[7];
    {
        int n = n0w + vsub; int nn = (n < NV) ? n : 0;
        const uint4* pp = (const uint4*)pairs + (size_t)nn * 7;
        #pragma unroll
        for (int j = 0; j < 7; j++) pr[j] = pp[j];
    }

    #pragma unroll
    for (int p = 0; p < 4; p++) {
        // issue all 27 gather loads
        uint2 u[27];
        #pragma unroll
        for (int m = 0; m < NM; m++) {
            unsigned int pm = comp(pr[m >> 2], m);
            unsigned int voff = ((pm & 0xffffu) << 7) + cofs;   // id*128 + cg*8
            u[m] = *(const uint2*)(xb + voff);
        }
        // prefetch next pass's pairs (overlaps accumulate)
        uint4 prn[7];
        if (p < 3) {
            int n2 = n0w + (p + 1) * 4 + vsub; int nn2 = (n2 < NV) ? n2 : 0;
            const uint4* pp = (const uint4*)pairs + (size_t)nn2 * 7;
            #pragma unroll
            for (int j = 0; j < 7; j++) prn[j] = pp[j];
        }
        // accumulate: packed fma, 4 channels/lane
        v2f acc[9][2];
        #pragma unroll
        for (int k = 0; k < 9; k++) { acc[k][0] = (v2f){0.f, 0.f}; acc[k][1] = (v2f){0.f, 0.f}; }
        #pragma unroll
        for (int m = 0; m < NM; m++) {
            unsigned int pm = comp(pr[m >> 2], m);
            float wv = bfbits(pm & 0xffff0000u);
            v2f w2 = {wv, wv};
            v2f x0 = {bfbits(u[m].x << 16), bfbits(u[m].x & 0xffff0000u)};
            v2f x1 = {bfbits(u[m].y << 16), bfbits(u[m].y & 0xffff0000u)};
            int k = m / 3;
            acc[k][0] = __builtin_elementwise_fma(x0, w2, acc[k][0]);
            acc[k][1] = __builtin_elementwise_fma(x1, w2, acc[k][1]);
        }
        // pack 4 channels x 9 k-slots -> LDS at t = k*64 + c
        int row = wave * 16 + p * 4 + vsub;
        unsigned short* dst = feat + row * ROW + cg * 4;
        #pragma unroll
        for (int k = 0; k < 9; k++) {
            unsigned int o2[2];
            o2[0] = pack_bf2(acc[k][0][0], acc[k][0][1]);
            o2[1] = pack_bf2(acc[k][1][0], acc[k][1][1]);
            *(uint2*)(dst + k * 64) = *(const uint2*)o2;
        }
        #pragma unroll
        for (int j = 0; j < 7; j++) pr[j] = prn[j];
    }
    __syncthreads();

    // ---- GEMM: A = feat (16 x 576) from LDS, B = Wp (64 x 576) from L1/L2
    int m = lane & 15, q = lane >> 4;
    const unsigned short* arow = feat + (size_t)(wave * 16 + m) * ROW + q * 8;
    const unsigned short* wrow = Wp + q * 8;
    f32x4 acc0 = {0.f, 0.f, 0.f, 0.f};
    f32x4 acc1 = {0.f, 0.f, 0.f, 0.f};
    f32x4 acc2 = {0.f, 0.f, 0.f, 0.f};
    f32x4 acc3 = {0.f, 0.f, 0.f, 0.f};
    #pragma unroll
    for (int kk = 0; kk < 18; kk++) {
        frag16 a  = *(const frag16*)(arow + kk * 32);
        frag16 b0 = *(const frag16*)(wrow + (size_t)(0 * 16 + m) * KP + kk * 32);
        frag16 b1 = *(const frag16*)(wrow + (size_t)(1 * 16 + m) * KP + kk * 32);
        frag16 b2 = *(const frag16*)(wrow + (size_t)(2 * 16 + m) * KP + kk * 32);
        frag16 b3 = *(const frag16*)(wrow + (size_t)(3 * 16 + m) * KP + kk * 32);
        acc0 = __builtin_amdgcn_mfma_f32_16x16x32_bf16(a, b0, acc0, 0, 0, 0);
        acc1 = __builtin_amdgcn_mfma_f32_16x16x32_bf16(a, b1, acc1, 0, 0, 0);
        acc2 = __builtin_amdgcn_mfma_f32_16x16x32_bf16(a, b2, acc2, 0, 0, 0);
        acc3 = __builtin_amdgcn_mfma_f32_16x16x32_bf16(a, b3, acc3, 0, 0, 0);
    }

    // ---- epilogue: D[row = q*4+i (vertex)][col = m+16j (output)], + bias
    size_t outb = (size_t)b * NO * NV;
    f32x4 accs[4] = {acc0, acc1, acc2, acc3};
    #pragma unroll
    for (int j = 0; j < 4; j++) {
        int o = j * 16 + m;
        float bo = bias[o];
        #pragma unroll
        for (int i = 0; i < 4; i++) {
            int n = n0w + q * 4 + i;
            if (n < NV) out[outb + (size_t)o * NV + n] = accs[j][i] + bo;
        }
    }
}

extern "C" void kernel_launch(void* const* d_in, const int* in_sizes, int n_in,
                              void* d_out, int out_size, void* d_ws, size_t ws_size,
                              hipStream_t stream) {
    const float* x    = (const float*)d_in[0];  // (4,64,40962) fp32
    const int*   nidx = (const int*)d_in[1];    // (40962,27) int32
    const float* nwt  = (const float*)d_in[2];  // (40962,27) fp32
    const float* W    = (const float*)d_in[3];  // (64,576) fp32
    const float* bias = (const float*)d_in[4];  // (64,) fp32
    float* out = (float*)d_out;                 // (4,64,40962) fp32

    unsigned short* Wp    = (unsigned short*)d_ws;                       // 72 KB
    unsigned short* xt    = (unsigned short*)((char*)d_ws + 131072);     // 21 MB
    unsigned int*   pairs = (unsigned int*)((char*)d_ws + 131072 + (size_t)NB * NV * NC * 2);  // 4.6 MB

    wprep_kernel<<<dim3((NO * KP + 255) / 256), 256, 0, stream>>>(W, Wp);
    pair_prep<<<dim3((NV * NPAD + 255) / 256), 256, 0, stream>>>(nidx, nwt, pairs);
    transpose_kernel<<<dim3((NV + 63) / 64, NB), 256, 0, stream>>>(x, xt);
    fused_kernel<<<dim3((NV + 31) / 32, NB), 128, 0, stream>>>(xt, pairs, Wp, bias, out);
}